// Round 2
// baseline (114.299 us; speedup 1.0000x reference)
//
#include <hip/hip_runtime.h>
#include <math.h>

// Shapes: S=4 B=8 N=2048 K=16 D=32 H=128; rows SBN=65536, rows/sb=2048.
// Single fused kernel: 64 n-rows per block, 512 threads (8 waves), grid 1024.
// LDS 30.5 KB x 4 blocks/CU = 125 KB; 4 blk x 8 waves = 32 waves/CU = 100%.
// (Round-1: 256 thr / 4 blk = 16 waves nominal, measured 31.6% occ, 42% VALU
//  -> latency-bound. This round doubles resident waves at identical math.)
typedef _Float16 half_t;
typedef __attribute__((ext_vector_type(8))) _Float16 half8;
typedef __attribute__((ext_vector_type(4))) _Float16 half4;

#define EXP2F(x) __builtin_amdgcn_exp2f(x)
#define RCPF(x)  __builtin_amdgcn_rcpf(x)
#define C_SCALE 2.8853900817779268f   // 2*log2(e): tanh(z)=1-2/(1+2^(c*z))

__global__ __launch_bounds__(512, 8) void fused_kernel(
    const float* __restrict__ x, const float* __restrict__ mu,
    const float* __restrict__ tau, const float* __restrict__ W1,
    const float* __restrict__ b1, const float* __restrict__ W2,
    float* __restrict__ out) {
  __shared__ __align__(16) float  sX[64][36];     // c*x tile (pad 36)
  __shared__ __align__(16) half_t sEx[64][136];   // f16 ex tile (272B rows)
  __shared__ __align__(16) half_t sEk[16][136];
  __shared__ __align__(16) half_t sW2[128];

  int t = threadIdx.x;
  int row0 = blockIdx.x * 64;
  int sb = row0 >> 11;

  // ---- stage c*x tile: 64x32 = 512 float4, one per thread, coalesced ----
  {
    const float4* x4 = (const float4*)(x + (size_t)row0 * 32);
    int n = t >> 3, d4 = t & 7;
    float4 v = x4[t];
    v.x *= C_SCALE; v.y *= C_SCALE; v.z *= C_SCALE; v.w *= C_SCALE;
    *(float4*)&sX[n][d4 * 4] = v;
  }
  // ---- stage w2h = f16(-2*W2) ----
  if (t < 16) {
    float4 a = ((const float4*)W2)[2 * t];
    float4 b = ((const float4*)W2)[2 * t + 1];
    half8 hv;
    hv[0] = (half_t)(-2.f * a.x); hv[1] = (half_t)(-2.f * a.y);
    hv[2] = (half_t)(-2.f * a.z); hv[3] = (half_t)(-2.f * a.w);
    hv[4] = (half_t)(-2.f * b.x); hv[5] = (half_t)(-2.f * b.y);
    hv[6] = (half_t)(-2.f * b.z); hv[7] = (half_t)(-2.f * b.w);
    *(half8*)&sW2[t * 8] = hv;
  }
  __syncthreads();

  // ---- phase 1: hx GEMM -> exp2 -> f16 LDS tile. 2 rows x 8 h per thread.
  //      Wx read from global (16 KB, cache-resident; broadcast across rg).
  {
    int hg = t & 15, rg = t >> 4;        // hg 0..15, rg 0..31
    int h0 = hg * 8, r0 = rg * 2;
    float acc[2][8];
#pragma unroll
    for (int j = 0; j < 2; ++j)
#pragma unroll
      for (int l = 0; l < 8; ++l) acc[j][l] = 0.f;
    const float* Wp = W1 + h0;
#pragma unroll 2
    for (int d = 0; d < 32; ++d) {
      float4 wa = *(const float4*)(Wp + d * 128);
      float4 wb = *(const float4*)(Wp + d * 128 + 4);
      float w[8] = {wa.x, wa.y, wa.z, wa.w, wb.x, wb.y, wb.z, wb.w};
#pragma unroll
      for (int j = 0; j < 2; ++j) {
        float xv = sX[r0 + j][d];        // broadcast among 16 lanes
#pragma unroll
        for (int l = 0; l < 8; ++l) acc[j][l] = fmaf(xv, w[l], acc[j][l]);
      }
    }
#pragma unroll
    for (int j = 0; j < 2; ++j) {
      half8 hv;
#pragma unroll
      for (int l = 0; l < 8; ++l) hv[l] = (half_t)EXP2F(acc[j][l]);
      *(half8*)&sEx[r0 + j][h0] = hv;
    }
  }

  // ---- ek: per-block recompute into sEk. 1 k x 4 h per thread.
  //      ek[k][h] = f16(exp2(c*(mu[k,:]@Wm[:,h] + tau[k,:]@Wt[:,h] + b1[h])))
  //      Per-h fma chain (d ascending, mu then tau per d) identical to before.
  {
    int k = t >> 5, h0 = (t & 31) * 4;
    const float4* mu4  = (const float4*)(mu  + ((size_t)sb * 16 + k) * 32);
    const float4* tau4 = (const float4*)(tau + ((size_t)sb * 16 + k) * 32);
    float acc[4];
    {
      float4 ba = *(const float4*)(b1 + h0);
      acc[0] = ba.x; acc[1] = ba.y; acc[2] = ba.z; acc[3] = ba.w;
    }
    const float* Wm = W1 + 32 * 128 + h0;
    const float* Wt = W1 + 64 * 128 + h0;
#pragma unroll 2
    for (int d4 = 0; d4 < 8; ++d4) {
      float4 m4 = mu4[d4], t4 = tau4[d4];
      float mv4[4] = {m4.x, m4.y, m4.z, m4.w};
      float tv4[4] = {t4.x, t4.y, t4.z, t4.w};
#pragma unroll
      for (int dd = 0; dd < 4; ++dd) {
        int d = d4 * 4 + dd;
        float4 wm = *(const float4*)(Wm + d * 128);
        float4 wt = *(const float4*)(Wt + d * 128);
        float wmv[4] = {wm.x, wm.y, wm.z, wm.w};
        float wtv[4] = {wt.x, wt.y, wt.z, wt.w};
        float mv = mv4[dd], tv = tv4[dd];
#pragma unroll
        for (int l = 0; l < 4; ++l) {
          acc[l] = fmaf(mv, wmv[l], acc[l]);
          acc[l] = fmaf(tv, wtv[l], acc[l]);
        }
      }
    }
    half4 hv;
#pragma unroll
    for (int l = 0; l < 4; ++l) hv[l] = (half_t)EXP2F(C_SCALE * acc[l]);
    *(half4*)&sEk[k][h0] = hv;
  }
  __syncthreads();

  // ---- phase 2: hot loop, 2 rows x 1 k per thread ----
  int kg = t & 15, rg = t >> 4;          // kg = k, rg 0..31
  int r0 = rg * 2;
  float a0 = 0.f, a1 = 0.f;
#pragma unroll 2
  for (int h8 = 0; h8 < 16; ++h8) {
    half8 ex0 = *(const half8*)&sEx[r0][h8 * 8];
    half8 ex1 = *(const half8*)&sEx[r0 + 1][h8 * 8];
    half8 ekv = *(const half8*)&sEk[kg][h8 * 8];
    half8 wv  = *(const half8*)&sW2[h8 * 8];
#pragma unroll
    for (int j = 0; j < 8; ++j) {
      float e0 = (float)ex0[j], e1 = (float)ex1[j];
      float f  = (float)ekv[j];
      float w  = (float)wv[j];
      a0 = fmaf(w, RCPF(fmaf(e0, f, 1.0f)), a0);
      a1 = fmaf(w, RCPF(fmaf(e1, f, 1.0f)), a1);
    }
  }

  // ---- softmax over k: 16 k across 16 contiguous lanes (shuffle width 16) --
  const float l2e = 1.4426950408889634f;
  {
    float m = a0;
#pragma unroll
    for (int s = 1; s < 16; s <<= 1) m = fmaxf(m, __shfl_xor(m, s, 16));
    float p = EXP2F((a0 - m) * l2e);
    float sum = p;
#pragma unroll
    for (int s = 1; s < 16; s <<= 1) sum += __shfl_xor(sum, s, 16);
    out[(size_t)(row0 + r0) * 16 + kg] = p * RCPF(sum);
  }
  {
    float m = a1;
#pragma unroll
    for (int s = 1; s < 16; s <<= 1) m = fmaxf(m, __shfl_xor(m, s, 16));
    float p = EXP2F((a1 - m) * l2e);
    float sum = p;
#pragma unroll
    for (int s = 1; s < 16; s <<= 1) sum += __shfl_xor(sum, s, 16);
    out[(size_t)(row0 + r0 + 1) * 16 + kg] = p * RCPF(sum);
  }
}

// ---------------------------------------------------------------------------
extern "C" void kernel_launch(void* const* d_in, const int* in_sizes, int n_in,
                              void* d_out, int out_size, void* d_ws, size_t ws_size,
                              hipStream_t stream) {
  const float* x   = (const float*)d_in[0];
  const float* mu  = (const float*)d_in[1];
  const float* tau = (const float*)d_in[2];
  const float* W1  = (const float*)d_in[3];
  const float* b1  = (const float*)d_in[4];
  const float* W2  = (const float*)d_in[5];
  // b2 (d_in[6]) and sum(W2) are k-uniform -> cancelled by softmax.
  float* out = (float*)d_out;
  (void)in_sizes; (void)n_in; (void)out_size; (void)d_ws; (void)ws_size;

  fused_kernel<<<1024, 512, 0, stream>>>(x, mu, tau, W1, b1, W2, out);
}

// Round 3
// 98.679 us; speedup vs baseline: 1.1583x; 1.1583x over previous
//
#include <hip/hip_runtime.h>
#include <math.h>

// Shapes: S=4 B=8 N=2048 K=16 D=32 H=128; rows SBN=65536, rows/sb=2048.
// Single fused kernel, 256 thr, 64 rows/block, grid 1024 = 4 blocks/CU exact.
// LDS 35.3 KB (sW aliased with sEx) -> 4 blocks/CU, no dispatch tail.
// R2 lesson: 512thr/launch_bounds(512,8) capped VGPR=32 -> spills (WRITE +2MB),
// 55.9us. R1 lesson: Wx from global (48KB W1 streams thru 32KB L1 x4 blocks)
// loses to LDS-staged sW. This round: R0's phase structure + fusion + aliasing.
typedef _Float16 half_t;
typedef __attribute__((ext_vector_type(8))) _Float16 half8;

#define EXP2F(x) __builtin_amdgcn_exp2f(x)
#define RCPF(x)  __builtin_amdgcn_rcpf(x)
#define C_SCALE 2.8853900817779268f   // 2*log2(e): tanh(z)=1-2/(1+2^(c*z))

__global__ __launch_bounds__(256, 4) void fused_kernel(
    const float* __restrict__ x, const float* __restrict__ mu,
    const float* __restrict__ tau, const float* __restrict__ W1,
    const float* __restrict__ b1, const float* __restrict__ W2,
    float* __restrict__ out) {
  __shared__ __align__(16) float sX[64][36];            // 9216 B, c*x tile
  // sU: phase1 = sW (32 rows x 560B, 16B-skewed every 4 lanes);
  //     phase2 = sEx (64 x 136 halfs, 272B rows). 17920 B, aliased.
  __shared__ __align__(16) unsigned char sU[32 * 560];
  __shared__ __align__(16) float sEk[16][132];          // 8448 B (f32 now)
  __shared__ __align__(16) float sW2[128];              // 512 B  (f32 now)

  int t = threadIdx.x;
  int row0 = blockIdx.x * 64;
  int sb = row0 >> 11;

  // ---- stage c*x tile: 64x32 = 512 float4, coalesced ----
  const float4* x4 = (const float4*)(x + (size_t)row0 * 32);
#pragma unroll
  for (int i = 0; i < 2; ++i) {
    int j = i * 256 + t;                 // 0..511
    int n = j >> 3, d4 = j & 7;
    float4 v = x4[j];
    v.x *= C_SCALE; v.y *= C_SCALE; v.z *= C_SCALE; v.w *= C_SCALE;
    *(float4*)&sX[n][d4 * 4] = v;
  }
  // ---- stage sW = Wx, bank-deconflicted: float4 f of row d goes to
  //      byte d*560 + f*16 + (f>>3)*16  (16B skew per 4 lanes -> 2-way max)
#pragma unroll
  for (int i = 0; i < 4; ++i) {
    int j = i * 256 + t;                 // 0..1023
    int d = j >> 5, f = j & 31;
    *(float4*)(sU + d * 560 + f * 16 + (f >> 3) * 16) = ((const float4*)W1)[j];
  }
  if (t < 128) sW2[t] = -2.0f * W2[t];

  // ---- ek -> sEk (f32). 1 k x 8 h per thread; global W reads, no LDS deps.
  {
    int k = t >> 4, h0 = (t & 15) * 8;
    const float4* mu4  = (const float4*)(mu  + ((size_t)sb * 16 + k) * 32);
    const float4* tau4 = (const float4*)(tau + ((size_t)sb * 16 + k) * 32);
    float acc[8];
    {
      float4 ba = *(const float4*)(b1 + h0);
      float4 bb = *(const float4*)(b1 + h0 + 4);
      acc[0] = ba.x; acc[1] = ba.y; acc[2] = ba.z; acc[3] = ba.w;
      acc[4] = bb.x; acc[5] = bb.y; acc[6] = bb.z; acc[7] = bb.w;
    }
    const float* Wm = W1 + 32 * 128 + h0;
    const float* Wt = W1 + 64 * 128 + h0;
#pragma unroll 2
    for (int d4 = 0; d4 < 8; ++d4) {
      float4 m4 = mu4[d4], t4 = tau4[d4];
      float mv4[4] = {m4.x, m4.y, m4.z, m4.w};
      float tv4[4] = {t4.x, t4.y, t4.z, t4.w};
#pragma unroll
      for (int dd = 0; dd < 4; ++dd) {
        int d = d4 * 4 + dd;
        float4 wma = *(const float4*)(Wm + d * 128);
        float4 wmb = *(const float4*)(Wm + d * 128 + 4);
        float4 wta = *(const float4*)(Wt + d * 128);
        float4 wtb = *(const float4*)(Wt + d * 128 + 4);
        float wm[8] = {wma.x, wma.y, wma.z, wma.w, wmb.x, wmb.y, wmb.z, wmb.w};
        float wt[8] = {wta.x, wta.y, wta.z, wta.w, wtb.x, wtb.y, wtb.z, wtb.w};
        float mv = mv4[dd], tv = tv4[dd];
#pragma unroll
        for (int l = 0; l < 8; ++l) {
          acc[l] = fmaf(mv, wm[l], acc[l]);
          acc[l] = fmaf(tv, wt[l], acc[l]);
        }
      }
    }
    float4 e0, e1;
    e0.x = EXP2F(C_SCALE * acc[0]); e0.y = EXP2F(C_SCALE * acc[1]);
    e0.z = EXP2F(C_SCALE * acc[2]); e0.w = EXP2F(C_SCALE * acc[3]);
    e1.x = EXP2F(C_SCALE * acc[4]); e1.y = EXP2F(C_SCALE * acc[5]);
    e1.z = EXP2F(C_SCALE * acc[6]); e1.w = EXP2F(C_SCALE * acc[7]);
    *(float4*)&sEk[k][h0] = e0;
    *(float4*)&sEk[k][h0 + 4] = e1;
  }
  __syncthreads();   // sX, sW, sW2, sEk all staged

  // ---- phase 1: hx GEMM from LDS sW -> exp2 -> f16 in REGISTERS ----
  int hg = t & 15, rg = t >> 4;          // 16 h-octs x 16 row-quads
  int h0 = hg * 8, r0 = rg * 4;
  half8 hv[4];
  {
    const unsigned char* wbase = sU + hg * 32 + (hg >> 2) * 16;
    float acc[4][8];
#pragma unroll
    for (int j = 0; j < 4; ++j)
#pragma unroll
      for (int l = 0; l < 8; ++l) acc[j][l] = 0.f;
#pragma unroll 4
    for (int d = 0; d < 32; ++d) {
      float4 wa = *(const float4*)(wbase + d * 560);
      float4 wb = *(const float4*)(wbase + d * 560 + 16);
      float w[8] = {wa.x, wa.y, wa.z, wa.w, wb.x, wb.y, wb.z, wb.w};
#pragma unroll
      for (int j = 0; j < 4; ++j) {
        float xv = sX[r0 + j][d];        // broadcast among 16 lanes
#pragma unroll
        for (int l = 0; l < 8; ++l) acc[j][l] = fmaf(xv, w[l], acc[j][l]);
      }
    }
#pragma unroll
    for (int j = 0; j < 4; ++j)
#pragma unroll
      for (int l = 0; l < 8; ++l) hv[j][l] = (half_t)EXP2F(acc[j][l]);
  }
  __syncthreads();   // all sW reads complete; safe to overwrite sU with sEx

  half_t (*sEx)[136] = (half_t(*)[136])sU;
#pragma unroll
  for (int j = 0; j < 4; ++j) *(half8*)&sEx[r0 + j][h0] = hv[j];
  __syncthreads();   // sEx visible

  // ---- phase 2: hot loop, 2 rows x 2 k per thread ----
  int kg = t & 7, rg2 = t >> 3;          // rg2 0..31
  int rp = rg2 * 2, k0 = kg * 2;
  float a00 = 0.f, a01 = 0.f, a10 = 0.f, a11 = 0.f;
#pragma unroll 2
  for (int h8 = 0; h8 < 16; ++h8) {
    half8 ex0 = *(const half8*)&sEx[rp][h8 * 8];
    half8 ex1 = *(const half8*)&sEx[rp + 1][h8 * 8];
    float4 f0a = *(const float4*)&sEk[k0][h8 * 8];
    float4 f0b = *(const float4*)&sEk[k0][h8 * 8 + 4];
    float4 f1a = *(const float4*)&sEk[k0 + 1][h8 * 8];
    float4 f1b = *(const float4*)&sEk[k0 + 1][h8 * 8 + 4];
    float4 wva = *(const float4*)&sW2[h8 * 8];
    float4 wvb = *(const float4*)&sW2[h8 * 8 + 4];
    float f0[8] = {f0a.x, f0a.y, f0a.z, f0a.w, f0b.x, f0b.y, f0b.z, f0b.w};
    float f1[8] = {f1a.x, f1a.y, f1a.z, f1a.w, f1b.x, f1b.y, f1b.z, f1b.w};
    float wv[8] = {wva.x, wva.y, wva.z, wva.w, wvb.x, wvb.y, wvb.z, wvb.w};
#pragma unroll
    for (int j = 0; j < 8; ++j) {
      float e0 = (float)ex0[j], e1 = (float)ex1[j];
      float w = wv[j];
      a00 = fmaf(w, RCPF(fmaf(e0, f0[j], 1.0f)), a00);
      a01 = fmaf(w, RCPF(fmaf(e0, f1[j], 1.0f)), a01);
      a10 = fmaf(w, RCPF(fmaf(e1, f0[j], 1.0f)), a10);
      a11 = fmaf(w, RCPF(fmaf(e1, f1[j], 1.0f)), a11);
    }
  }

  // ---- softmax over k: 2 k in-thread x 8 kg-lanes (shuffle width 8) ----
  const float l2e = 1.4426950408889634f;
  {
    float m = fmaxf(a00, a01);
#pragma unroll
    for (int s = 1; s < 8; s <<= 1) m = fmaxf(m, __shfl_xor(m, s, 8));
    float p0 = EXP2F((a00 - m) * l2e), p1 = EXP2F((a01 - m) * l2e);
    float sum = p0 + p1;
#pragma unroll
    for (int s = 1; s < 8; s <<= 1) sum += __shfl_xor(sum, s, 8);
    float inv = RCPF(sum);
    float2 o = make_float2(p0 * inv, p1 * inv);
    *(float2*)&out[(size_t)(row0 + rp) * 16 + k0] = o;
  }
  {
    float m = fmaxf(a10, a11);
#pragma unroll
    for (int s = 1; s < 8; s <<= 1) m = fmaxf(m, __shfl_xor(m, s, 8));
    float p0 = EXP2F((a10 - m) * l2e), p1 = EXP2F((a11 - m) * l2e);
    float sum = p0 + p1;
#pragma unroll
    for (int s = 1; s < 8; s <<= 1) sum += __shfl_xor(sum, s, 8);
    float inv = RCPF(sum);
    float2 o = make_float2(p0 * inv, p1 * inv);
    *(float2*)&out[(size_t)(row0 + rp + 1) * 16 + k0] = o;
  }
}

// ---------------------------------------------------------------------------
extern "C" void kernel_launch(void* const* d_in, const int* in_sizes, int n_in,
                              void* d_out, int out_size, void* d_ws, size_t ws_size,
                              hipStream_t stream) {
  const float* x   = (const float*)d_in[0];
  const float* mu  = (const float*)d_in[1];
  const float* tau = (const float*)d_in[2];
  const float* W1  = (const float*)d_in[3];
  const float* b1  = (const float*)d_in[4];
  const float* W2  = (const float*)d_in[5];
  // b2 (d_in[6]) and sum(W2) are k-uniform -> cancelled by softmax.
  float* out = (float*)d_out;
  (void)in_sizes; (void)n_in; (void)out_size; (void)d_ws; (void)ws_size;

  fused_kernel<<<1024, 256, 0, stream>>>(x, mu, tau, W1, b1, W2, out);
}

// Round 4
// 97.679 us; speedup vs baseline: 1.1702x; 1.0102x over previous
//
#include <hip/hip_runtime.h>
#include <math.h>

// Shapes: S=4 B=8 N=2048 K=16 D=32 H=128; rows SBN=65536, rows/sb=2048.
// R4: 128-row tiles, 512 thr (8 waves), grid 512 = 2 blocks/CU exact.
//  - halves per-CU W-staging + ek recompute vs 64-row tiles
//  - sEk/sW2 f16 (R1-validated numerics) -> 5 LDS reads per (2r,2k) quad
//  - phase-2 fully unrolled, immediate ds offsets (kills address VALU)
//  - launch_bounds(512,4): VGPR cap 128 (R2's (512,8) cap 64 caused spills)
// LDS: sX 18432 + sU max(17920,34816) + sEk 4352 + sW2 256 = 57856 B x2/CU.
typedef _Float16 half_t;
typedef __attribute__((ext_vector_type(8))) _Float16 half8;
typedef __attribute__((ext_vector_type(4))) _Float16 half4;

#define EXP2F(x) __builtin_amdgcn_exp2f(x)
#define RCPF(x)  __builtin_amdgcn_rcpf(x)
#define C_SCALE 2.8853900817779268f   // 2*log2(e): tanh(z)=1-2/(1+2^(c*z))

__global__ __launch_bounds__(512, 4) void fused_kernel(
    const float* __restrict__ x, const float* __restrict__ mu,
    const float* __restrict__ tau, const float* __restrict__ W1,
    const float* __restrict__ b1, const float* __restrict__ W2,
    float* __restrict__ out) {
  __shared__ __align__(16) float sX[128][36];           // 18432 B, c*x tile
  // sU: phase1 = sW (32 rows x 560B, 16B skew per 4 float4s);
  //     phase2 = sEx (128 x 136 halfs, 272B rows). 34816 B, aliased.
  __shared__ __align__(16) unsigned char sU[128 * 272];
  __shared__ __align__(16) half_t sEk[16][136];         // 4352 B (f16, R1-ok)
  __shared__ __align__(16) half_t sW2[128];             // 256 B  (f16, R1-ok)

  int t = threadIdx.x;
  int row0 = blockIdx.x * 128;
  int sb = row0 >> 11;

  // ---- stage c*x tile: 128x32 = 1024 float4, coalesced ----
  const float4* x4 = (const float4*)(x + (size_t)row0 * 32);
#pragma unroll
  for (int i = 0; i < 2; ++i) {
    int j = i * 512 + t;                 // 0..1023
    int n = j >> 3, d4 = j & 7;
    float4 v = x4[j];
    v.x *= C_SCALE; v.y *= C_SCALE; v.z *= C_SCALE; v.w *= C_SCALE;
    *(float4*)&sX[n][d4 * 4] = v;
  }
  // ---- stage sW = Wx, bank-deconflicted: float4 f of row d at
  //      byte d*560 + f*16 + (f>>3)*16 (16B skew per 8 float4s -> 2-way max)
#pragma unroll
  for (int i = 0; i < 2; ++i) {
    int j = i * 512 + t;                 // 0..1023
    int d = j >> 5, f = j & 31;
    *(float4*)(sU + d * 560 + f * 16 + (f >> 3) * 16) = ((const float4*)W1)[j];
  }
  // ---- stage w2h = f16(-2*W2) ----
  if (t < 16) {
    float4 a = ((const float4*)W2)[2 * t];
    float4 b = ((const float4*)W2)[2 * t + 1];
    half8 hv;
    hv[0] = (half_t)(-2.f * a.x); hv[1] = (half_t)(-2.f * a.y);
    hv[2] = (half_t)(-2.f * a.z); hv[3] = (half_t)(-2.f * a.w);
    hv[4] = (half_t)(-2.f * b.x); hv[5] = (half_t)(-2.f * b.y);
    hv[6] = (half_t)(-2.f * b.z); hv[7] = (half_t)(-2.f * b.w);
    *(half8*)&sW2[t * 8] = hv;
  }

  // ---- ek -> sEk (f16). 1 k x 4 h per thread (512 thr = 16k x 32 hquads).
  //      Per-h chain: d ascending, mu-then-tau per d (bit-identical to R1/R3).
  {
    int k = t >> 5, h0 = (t & 31) * 4;
    const float4* mu4  = (const float4*)(mu  + ((size_t)sb * 16 + k) * 32);
    const float4* tau4 = (const float4*)(tau + ((size_t)sb * 16 + k) * 32);
    float acc[4];
    {
      float4 ba = *(const float4*)(b1 + h0);
      acc[0] = ba.x; acc[1] = ba.y; acc[2] = ba.z; acc[3] = ba.w;
    }
    const float* Wm = W1 + 32 * 128 + h0;
    const float* Wt = W1 + 64 * 128 + h0;
#pragma unroll 2
    for (int d4 = 0; d4 < 8; ++d4) {
      float4 m4 = mu4[d4], t4 = tau4[d4];
      float mv4[4] = {m4.x, m4.y, m4.z, m4.w};
      float tv4[4] = {t4.x, t4.y, t4.z, t4.w};
#pragma unroll
      for (int dd = 0; dd < 4; ++dd) {
        int d = d4 * 4 + dd;
        float4 wm = *(const float4*)(Wm + d * 128);
        float4 wt = *(const float4*)(Wt + d * 128);
        float wmv[4] = {wm.x, wm.y, wm.z, wm.w};
        float wtv[4] = {wt.x, wt.y, wt.z, wt.w};
        float mv = mv4[dd], tv = tv4[dd];
#pragma unroll
        for (int l = 0; l < 4; ++l) {
          acc[l] = fmaf(mv, wmv[l], acc[l]);
          acc[l] = fmaf(tv, wtv[l], acc[l]);
        }
      }
    }
    half4 hv;
#pragma unroll
    for (int l = 0; l < 4; ++l) hv[l] = (half_t)EXP2F(C_SCALE * acc[l]);
    *(half4*)&sEk[k][h0] = hv;
  }
  __syncthreads();   // sX, sW, sW2, sEk staged

  // ---- phase 1: hx GEMM from LDS -> exp2 -> f16 regs. 4 rows x 8 h/thread.
  int hg = t & 15, rg = t >> 4;          // hg 0..15, rg 0..31
  int h0 = hg * 8, r0 = rg * 4;
  half8 hv[4];
  {
    const unsigned char* wbase = sU + hg * 32 + (hg >> 2) * 16;
    float acc[4][8];
#pragma unroll
    for (int j = 0; j < 4; ++j)
#pragma unroll
      for (int l = 0; l < 8; ++l) acc[j][l] = 0.f;
#pragma unroll 4
    for (int d = 0; d < 32; ++d) {
      float4 wa = *(const float4*)(wbase + d * 560);
      float4 wb = *(const float4*)(wbase + d * 560 + 16);
      float w[8] = {wa.x, wa.y, wa.z, wa.w, wb.x, wb.y, wb.z, wb.w};
#pragma unroll
      for (int j = 0; j < 4; ++j) {
        float xv = sX[r0 + j][d];        // broadcast among 16 lanes
#pragma unroll
        for (int l = 0; l < 8; ++l) acc[j][l] = fmaf(xv, w[l], acc[j][l]);
      }
    }
#pragma unroll
    for (int j = 0; j < 4; ++j)
#pragma unroll
      for (int l = 0; l < 8; ++l) hv[j][l] = (half_t)EXP2F(acc[j][l]);
  }
  __syncthreads();   // all sW reads done; safe to overwrite sU with sEx

  half_t (*sEx)[136] = (half_t(*)[136])sU;
#pragma unroll
  for (int j = 0; j < 4; ++j) *(half8*)&sEx[r0 + j][h0] = hv[j];
  __syncthreads();   // sEx visible

  // ---- phase 2: hot loop, 2 rows x 2 k per thread, fully unrolled ----
  int kg = t & 7, rg2 = t >> 3;          // rg2 0..63
  int rp = rg2 * 2, k0 = kg * 2;
  const half_t* exr0 = &sEx[rp][0];
  const half_t* exr1 = &sEx[rp + 1][0];
  const half_t* ekr0 = &sEk[k0][0];
  const half_t* ekr1 = &sEk[k0 + 1][0];
  float a00 = 0.f, a01 = 0.f, a10 = 0.f, a11 = 0.f;
#pragma unroll
  for (int h8 = 0; h8 < 16; ++h8) {
    half8 ex0  = *(const half8*)(exr0 + h8 * 8);
    half8 ex1  = *(const half8*)(exr1 + h8 * 8);
    half8 ekv0 = *(const half8*)(ekr0 + h8 * 8);
    half8 ekv1 = *(const half8*)(ekr1 + h8 * 8);
    half8 wv   = *(const half8*)(&sW2[h8 * 8]);
#pragma unroll
    for (int j = 0; j < 8; ++j) {
      float e0 = (float)ex0[j], e1 = (float)ex1[j];
      float f0 = (float)ekv0[j], f1 = (float)ekv1[j];
      float w  = (float)wv[j];
      a00 = fmaf(w, RCPF(fmaf(e0, f0, 1.0f)), a00);
      a01 = fmaf(w, RCPF(fmaf(e0, f1, 1.0f)), a01);
      a10 = fmaf(w, RCPF(fmaf(e1, f0, 1.0f)), a10);
      a11 = fmaf(w, RCPF(fmaf(e1, f1, 1.0f)), a11);
    }
  }

  // ---- softmax over k: 2 k in-thread x 8 kg-lanes (shuffle width 8) ----
  const float l2e = 1.4426950408889634f;
  {
    float m = fmaxf(a00, a01);
#pragma unroll
    for (int s = 1; s < 8; s <<= 1) m = fmaxf(m, __shfl_xor(m, s, 8));
    float p0 = EXP2F((a00 - m) * l2e), p1 = EXP2F((a01 - m) * l2e);
    float sum = p0 + p1;
#pragma unroll
    for (int s = 1; s < 8; s <<= 1) sum += __shfl_xor(sum, s, 8);
    float inv = RCPF(sum);
    float2 o = make_float2(p0 * inv, p1 * inv);
    *(float2*)&out[(size_t)(row0 + rp) * 16 + k0] = o;
  }
  {
    float m = fmaxf(a10, a11);
#pragma unroll
    for (int s = 1; s < 8; s <<= 1) m = fmaxf(m, __shfl_xor(m, s, 8));
    float p0 = EXP2F((a10 - m) * l2e), p1 = EXP2F((a11 - m) * l2e);
    float sum = p0 + p1;
#pragma unroll
    for (int s = 1; s < 8; s <<= 1) sum += __shfl_xor(sum, s, 8);
    float inv = RCPF(sum);
    float2 o = make_float2(p0 * inv, p1 * inv);
    *(float2*)&out[(size_t)(row0 + rp + 1) * 16 + k0] = o;
  }
}

// ---------------------------------------------------------------------------
extern "C" void kernel_launch(void* const* d_in, const int* in_sizes, int n_in,
                              void* d_out, int out_size, void* d_ws, size_t ws_size,
                              hipStream_t stream) {
  const float* x   = (const float*)d_in[0];
  const float* mu  = (const float*)d_in[1];
  const float* tau = (const float*)d_in[2];
  const float* W1  = (const float*)d_in[3];
  const float* b1  = (const float*)d_in[4];
  const float* W2  = (const float*)d_in[5];
  // b2 (d_in[6]) and sum(W2) are k-uniform -> cancelled by softmax.
  float* out = (float*)d_out;
  (void)in_sizes; (void)n_in; (void)out_size; (void)d_ws; (void)ws_size;

  fused_kernel<<<512, 512, 0, stream>>>(x, mu, tau, W1, b1, W2, out);
}